// Round 6
// baseline (179.948 us; speedup 1.0000x reference)
//
#include <hip/hip_runtime.h>
#include <math.h>

#define BB 2
#define NN 6
#define CC 64
#define HH 32
#define WW 88
#define HC 7
#define DG 128
#define HWP (HH*WW)      // 2816
#define GSTR 129
#define OUTCH (CC*HC)    // 448
#define CSTRIDE (HC*DG*DG) // 114688

// ---------------------------------------------------------------------------
// Transpose features (B,N,C,H,W) -> featT (B,N,H,W,C) so channels are
// contiguous (float4-gatherable). One wave per (b,n,h): lane = channel.
// ---------------------------------------------------------------------------
__global__ __launch_bounds__(256) void transpose_feat_kernel(
    const float* __restrict__ f, float* __restrict__ ft) {
  int gw = blockIdx.x * 4 + (threadIdx.x >> 6);   // 0 .. B*N*H-1 = 383
  int lane = threadIdx.x & 63;                    // channel
  int bn = gw / HH;
  int h  = gw % HH;
  const float* src = f + ((size_t)bn * CC + lane) * HWP + (size_t)h * WW;
  float* dst = ft + ((size_t)bn * HWP + (size_t)h * WW) * CC + lane;
  for (int w = 0; w < WW; ++w) dst[(size_t)w * CC] = src[w];
}

// ---------------------------------------------------------------------------
// Main kernel. Block = (128,2): tx = w (BEV col), ty selects one of 2 d rows.
// grid = B*HC*64 blocks. Camera params + behind-camera constant samples are
// built per-block in LDS.
// ---------------------------------------------------------------------------
template<bool TRANS>
__global__ __launch_bounds__(256) void oft_main_kernel(
    const float* __restrict__ feats,   // (B,N,C,H,W)
    const float* __restrict__ featT,   // (B,N,H,W,C) or == feats when !TRANS
    const float* __restrict__ ks,      // (B,N,3,3)
    const float* __restrict__ imu,     // (B,N,3,4)
    const float* __restrict__ prots,   // (B,N,3,3)
    const float* __restrict__ ptrans,  // (B,N,3)
    const float* __restrict__ und,     // (B,N,7)
    const float* __restrict__ grid,    // (B,129,129,3)
    float* __restrict__ out) {         // (B,448,128,128)
  __shared__ float s_par[NN * 32];
  __shared__ __align__(16) float s_beh[NN * CC];

  int blk = blockIdx.x;
  int b  = blk / (HC * 64);
  int r  = blk % (HC * 64);
  int hc = r / 64;
  int d  = (r % 64) * 2 + threadIdx.y;
  int w  = threadIdx.x;
  int tid = threadIdx.y * 128 + threadIdx.x;

  // --- per-block camera param build (threads 0..5, one cam each) ---
  if (tid < NN) {
    int n = tid;
    int cam = b * NN + n;
    const float* K = ks + cam * 9;
    const float* M = imu + cam * 12;
    float* P = &s_par[n * 32];
    #pragma unroll
    for (int i = 0; i < 3; ++i)
      #pragma unroll
      for (int k = 0; k < 4; ++k)
        P[i * 4 + k] = K[i*3+0]*M[0*4+k] + K[i*3+1]*M[1*4+k] + K[i*3+2]*M[2*4+k];
    P[12] = K[0]; P[13] = K[4]; P[14] = K[2]; P[15] = K[5];  // fx fy cx cy
    const float* u = und + cam * 7;
    #pragma unroll
    for (int i = 0; i < 6; ++i) P[16 + i] = u[i];
    P[23] = u[6];                                            // fisheye flag
    const float* R = prots + cam * 9;
    P[24] = R[0]; P[25] = R[1]; P[26] = R[3]; P[27] = R[4];
    const float* T = ptrans + cam * 3;
    P[28] = T[0]; P[29] = T[1];
    // behind-camera coords: dist=(0,0) exactly (masked), pts2 = post_trans
    float nx = fminf(fmaxf(2.0f * T[0] / 88.0f - 1.0f, -1.f), 1.f);
    float ny = fminf(fmaxf(2.0f * T[1] / 88.0f - 1.0f, -1.f), 1.f);
    bool vis = (nx > -1.f) && (nx < 1.f) && (ny > -1.f) && (ny < 1.f);
    P[30] = vis ? 1.f : 0.f;
    P[31] = 0.f;
  }
  __syncthreads();

  // --- behind-camera constant sample per (cam, channel): 384 entries,
  //     256 threads -> strided loop (BUGFIX: was `if (tid < 384)` which
  //     left cameras 4,5 uninitialized) ---
  for (int t = tid; t < NN * CC; t += 256) {
    int n = t / CC, c = t % CC;
    const float* P = &s_par[n * 32];
    float val = 0.f;
    if (P[30] != 0.f) {
      float nx = fminf(fmaxf(2.0f * P[28] / 88.0f - 1.0f, -1.f), 1.f);
      float ny = fminf(fmaxf(2.0f * P[29] / 88.0f - 1.0f, -1.f), 1.f);
      float gx = (nx + 1.f) * 0.5f * (float)(WW - 1);
      float gy = (ny + 1.f) * 0.5f * (float)(HH - 1);
      float x0f = floorf(gx), y0f = floorf(gy);
      float wx = gx - x0f, wy = gy - y0f;
      int x0 = (int)fminf(fmaxf(x0f,        0.f), (float)(WW - 1));
      int x1 = (int)fminf(fmaxf(x0f + 1.f,  0.f), (float)(WW - 1));
      int y0 = (int)fminf(fmaxf(y0f,        0.f), (float)(HH - 1));
      int y1 = (int)fminf(fmaxf(y0f + 1.f,  0.f), (float)(HH - 1));
      const float* fb = feats + ((size_t)(b * NN + n) * CC + c) * HWP;
      float w00 = (1.f - wx) * (1.f - wy), w01 = wx * (1.f - wy);
      float w10 = (1.f - wx) * wy,         w11 = wx * wy;
      val = fb[y0*WW+x0]*w00 + fb[y0*WW+x1]*w01 + fb[y1*WW+x0]*w10 + fb[y1*WW+x1]*w11;
    }
    s_beh[t] = val;
  }
  __syncthreads();

  // --- BEV corner point ---
  size_t gidx = (((size_t)b * GSTR + d) * GSTR + w) * 3;
  float px = grid[gidx];
  float py = grid[gidx + 1] + (2.0f - 0.5f * (float)hc);
  float pz = grid[gidx + 2];

  // --- per-camera projection: mode 0 = contributes 0, 1 = sample, 2 = behind ---
  int   mode[NN];
  int   off[NN];
  float fwx[NN], fwy[NN];
  bool any0 = false;
  #pragma unroll
  for (int n = 0; n < NN; ++n) {
    const float* P = &s_par[n * 32];
    float hz = P[8]*px + P[9]*py + P[10]*pz + P[11];
    int md = 0;
    if (hz > 0.f) {
      float hx = P[0]*px + P[1]*py + P[2]*pz + P[3];
      float hy = P[4]*px + P[5]*py + P[6]*pz + P[7];
      float ptx = hx / hz, pty = hy / hz;
      float fx = P[12], fy = P[13], cx = P[14], cy = P[15];
      float xn = (ptx - cx) / fx, yn = (pty - cy) / fy;
      float dx, dy;
      if (P[23] == 1.0f) {   // fisheye (uniform per cam)
        float r2 = xn*xn + yn*yn;
        float rr = sqrtf(r2);
        float th = atanf(rr);
        float t2 = th*th, t4 = t2*t2;
        float poly = 1.f + P[16]*t2 + P[17]*t4 + P[18]*(t4*t2) + P[21]*(t4*t4);
        float rad = th * poly / rr;
        dx = xn * rad * fx + cx;
        dy = yn * rad * fy + cy;
      } else {               // pinhole
        float r2 = xn*xn + yn*yn;
        float radial = 1.f + P[16]*r2 + P[17]*r2*r2 + P[18]*r2*r2*r2;
        float xp = xn*radial + 2.f*P[19]*xn*yn + P[20]*(r2 + 2.f*xn*xn);
        float yp = yn*radial + P[19]*(r2 + 2.f*yn*yn) + 2.f*P[20]*xn*yn;
        dx = xp * fx + cx;
        dy = yp * fy + cy;
      }
      float p2x = P[24]*dx + P[25]*dy + P[28];
      float p2y = P[26]*dx + P[27]*dy + P[29];
      float nx = fminf(fmaxf(2.0f * p2x / 88.0f - 1.0f, -1.f), 1.f);
      float ny = fminf(fmaxf(2.0f * p2y / 88.0f - 1.0f, -1.f), 1.f);
      bool visible = (nx > -1.f) && (nx < 1.f) && (ny > -1.f) && (ny < 1.f);
      if (visible) {
        float gx = (nx + 1.f) * 0.5f * (float)(WW - 1);
        float gy = (ny + 1.f) * 0.5f * (float)(HH - 1);
        float x0f = floorf(gx), y0f = floorf(gy);
        fwx[n] = gx - x0f;
        fwy[n] = gy - y0f;
        int x0 = (int)fminf(fmaxf(x0f, 0.f), (float)(WW - 1));
        int y0 = (int)fminf(fmaxf(y0f, 0.f), (float)(HH - 1));
        off[n] = y0 * WW + x0;
        md = 1;
      } else {
        any0 = true;
      }
    } else {
      if (P[30] != 0.f) md = 2; else any0 = true;
    }
    mode[n] = md;
  }

  // --- channel loop: max over cameras ---
  float acc[CC];
  float init = any0 ? 0.f : -INFINITY;
  #pragma unroll
  for (int c = 0; c < CC; ++c) acc[c] = init;

  #pragma unroll
  for (int n = 0; n < NN; ++n) {
    if (mode[n] == 1) {
      float wxv = fwx[n], wyv = fwy[n];
      float w00 = (1.f - wxv) * (1.f - wyv), w01 = wxv * (1.f - wyv);
      float w10 = (1.f - wxv) * wyv,         w11 = wxv * wyv;
      if (TRANS) {
        const float4* t00 = (const float4*)(featT + ((size_t)(b*NN+n)*HWP + off[n]) * CC);
        const float4* t01 = t00 + CC/4;
        const float4* t10 = t00 + (WW*CC)/4;
        const float4* t11 = t10 + CC/4;
        #pragma unroll
        for (int j = 0; j < CC/4; ++j) {
          float4 a = t00[j], e = t01[j], f2 = t10[j], g = t11[j];
          acc[4*j+0] = fmaxf(acc[4*j+0], a.x*w00 + e.x*w01 + f2.x*w10 + g.x*w11);
          acc[4*j+1] = fmaxf(acc[4*j+1], a.y*w00 + e.y*w01 + f2.y*w10 + g.y*w11);
          acc[4*j+2] = fmaxf(acc[4*j+2], a.z*w00 + e.z*w01 + f2.z*w10 + g.z*w11);
          acc[4*j+3] = fmaxf(acc[4*j+3], a.w*w00 + e.w*w01 + f2.w*w10 + g.w*w11);
        }
      } else {
        const float* fb = feats + (size_t)(b*NN+n) * CC * HWP + off[n];
        #pragma unroll
        for (int c = 0; c < CC; ++c) {
          const float* p = fb + (size_t)c * HWP;
          float v = p[0]*w00 + p[1]*w01 + p[WW]*w10 + p[WW+1]*w11;
          acc[c] = fmaxf(acc[c], v);
        }
      }
    } else if (mode[n] == 2) {
      const float* bp = &s_beh[n * CC];
      #pragma unroll
      for (int c = 0; c < CC; ++c) acc[c] = fmaxf(acc[c], bp[c]);
    }
  }

  // --- write out[b, c*7+hc, d, w] ---
  float* op = out + (((size_t)b * OUTCH + hc) * DG + d) * DG + w;
  #pragma unroll
  for (int c = 0; c < CC; ++c) op[(size_t)c * CSTRIDE] = acc[c];
}

extern "C" void kernel_launch(void* const* d_in, const int* in_sizes, int n_in,
                              void* d_out, int out_size, void* d_ws, size_t ws_size,
                              hipStream_t stream) {
  const float* feats  = (const float*)d_in[0];
  const float* ks     = (const float*)d_in[1];
  const float* imu    = (const float*)d_in[2];
  const float* prots  = (const float*)d_in[3];
  const float* ptrans = (const float*)d_in[4];
  const float* und    = (const float*)d_in[5];
  const float* grid   = (const float*)d_in[6];
  float* out = (float*)d_out;

  size_t featT_bytes = (size_t)BB * NN * HH * WW * CC * sizeof(float);
  bool trans = (d_ws != nullptr) && (ws_size >= featT_bytes);
  float* featT = (float*)d_ws;

  dim3 mblock(128, 2);
  dim3 mgrid(BB * HC * 64);

  if (trans) {
    transpose_feat_kernel<<<96, 256, 0, stream>>>(feats, featT);
    oft_main_kernel<true><<<mgrid, mblock, 0, stream>>>(
        feats, featT, ks, imu, prots, ptrans, und, grid, out);
  } else {
    oft_main_kernel<false><<<mgrid, mblock, 0, stream>>>(
        feats, feats, ks, imu, prots, ptrans, und, grid, out);
  }
}

// Round 9
// 125.512 us; speedup vs baseline: 1.4337x; 1.4337x over previous
//
#include <hip/hip_runtime.h>
#include <math.h>

typedef _Float16 h2 __attribute__((ext_vector_type(2)));

#define BB 2
#define NN 6
#define CC 64
#define HH 32
#define WW 88
#define HC 7
#define DG 128
#define HWP (HH*WW)      // 2816
#define GSTR 129
#define OUTCH (CC*HC)    // 448
#define CSTRIDE (HC*DG*DG) // 114688

// ---------------------------------------------------------------------------
// Transpose+downconvert: features (B,N,C,H,W) fp32 -> featT (B,N,H*W,C) fp16.
// LDS-tiled: block = 64 pixels x 64 channels, both sides coalesced.
// grid = B*N*44 blocks (44 = 2816/64) x 256 threads.
// ---------------------------------------------------------------------------
__global__ __launch_bounds__(256) void transpose_feat_f16_kernel(
    const float* __restrict__ f, _Float16* __restrict__ ft) {
  __shared__ float lds[64 * 65];   // +1 pad: conflict-free both phases
  int blk = blockIdx.x;
  int bn = blk / 44;
  int pxbase = (blk % 44) * 64;
  int tid = threadIdx.x;
  // read: per wave, fixed ch, lanes = consecutive px -> 256B coalesced
  #pragma unroll
  for (int i = 0; i < 16; ++i) {
    int idx = i * 256 + tid;
    int ch = idx >> 6, px = idx & 63;
    lds[px * 65 + ch] = f[((size_t)bn * CC + ch) * HWP + pxbase + px];
  }
  __syncthreads();
  // write: thread t -> pixel t>>2, 16 channels; wave covers 2KB contiguous
  int px = tid >> 2, cg = (tid & 3) * 16;
  union { h2 hv[8]; int4 v4[2]; } u;
  #pragma unroll
  for (int k = 0; k < 8; ++k) {
    float lo = lds[px * 65 + cg + 2 * k];
    float hi = lds[px * 65 + cg + 2 * k + 1];
    u.hv[k] = (h2){(_Float16)lo, (_Float16)hi};
  }
  int4* dst = (int4*)(ft + ((size_t)bn * HWP + pxbase + px) * CC + cg);
  dst[0] = u.v4[0];
  dst[1] = u.v4[1];
}

// ---------------------------------------------------------------------------
// Main kernel. Block = (128,2): tx = w (BEV col), ty = one of 2 d rows.
// grid = B*HC*64 blocks. fp16 gather, packed-fp16 bilinear+max.
// ---------------------------------------------------------------------------
template<bool TRANS>
__global__ __launch_bounds__(256) void oft_main_kernel(
    const float* __restrict__ feats,   // (B,N,C,H,W) fp32
    const _Float16* __restrict__ featT,// (B,N,H*W,C) fp16
    const float* __restrict__ ks, const float* __restrict__ imu,
    const float* __restrict__ prots, const float* __restrict__ ptrans,
    const float* __restrict__ und, const float* __restrict__ grid,
    float* __restrict__ out) {         // (B,448,128,128)
  __shared__ float s_par[NN * 32];
  __shared__ __align__(16) h2 s_beh2[NN * 32];  // per (cam, ch-pair)

  int blk = blockIdx.x;
  int b  = blk / (HC * 64);
  int r  = blk % (HC * 64);
  int hc = r / 64;
  int d  = (r % 64) * 2 + threadIdx.y;
  int w  = threadIdx.x;
  int tid = threadIdx.y * 128 + threadIdx.x;

  // --- per-block camera params (threads 0..5) ---
  if (tid < NN) {
    int n = tid;
    int cam = b * NN + n;
    const float* K = ks + cam * 9;
    const float* M = imu + cam * 12;
    float* P = &s_par[n * 32];
    #pragma unroll
    for (int i = 0; i < 3; ++i)
      #pragma unroll
      for (int k = 0; k < 4; ++k)
        P[i * 4 + k] = K[i*3+0]*M[0*4+k] + K[i*3+1]*M[1*4+k] + K[i*3+2]*M[2*4+k];
    P[12] = K[0]; P[13] = K[4]; P[14] = K[2]; P[15] = K[5];
    const float* u = und + cam * 7;
    #pragma unroll
    for (int i = 0; i < 6; ++i) P[16 + i] = u[i];
    P[23] = u[6];
    const float* R = prots + cam * 9;
    P[24] = R[0]; P[25] = R[1]; P[26] = R[3]; P[27] = R[4];
    const float* T = ptrans + cam * 3;
    P[28] = T[0]; P[29] = T[1];
    float nx = fminf(fmaxf(2.0f * T[0] / 88.0f - 1.0f, -1.f), 1.f);
    float ny = fminf(fmaxf(2.0f * T[1] / 88.0f - 1.0f, -1.f), 1.f);
    bool vis = (nx > -1.f) && (nx < 1.f) && (ny > -1.f) && (ny < 1.f);
    P[30] = vis ? 1.f : 0.f;
    P[31] = 0.f;
  }
  __syncthreads();

  // --- behind-camera constant sample per (cam, ch-pair): 192 entries ---
  if (tid < NN * 32) {
    int n = tid >> 5, m = tid & 31;
    const float* P = &s_par[n * 32];
    float v0 = 0.f, v1 = 0.f;
    if (P[30] != 0.f) {
      float nx = fminf(fmaxf(2.0f * P[28] / 88.0f - 1.0f, -1.f), 1.f);
      float ny = fminf(fmaxf(2.0f * P[29] / 88.0f - 1.0f, -1.f), 1.f);
      float gx = (nx + 1.f) * 0.5f * (float)(WW - 1);
      float gy = (ny + 1.f) * 0.5f * (float)(HH - 1);
      float x0f = floorf(gx), y0f = floorf(gy);
      float wx = gx - x0f, wy = gy - y0f;
      int x0 = (int)fminf(fmaxf(x0f,        0.f), (float)(WW - 1));
      int x1 = (int)fminf(fmaxf(x0f + 1.f,  0.f), (float)(WW - 1));
      int y0 = (int)fminf(fmaxf(y0f,        0.f), (float)(HH - 1));
      int y1 = (int)fminf(fmaxf(y0f + 1.f,  0.f), (float)(HH - 1));
      float w00 = (1.f - wx) * (1.f - wy), w01 = wx * (1.f - wy);
      float w10 = (1.f - wx) * wy,         w11 = wx * wy;
      const float* fb0 = feats + ((size_t)(b * NN + n) * CC + 2*m) * HWP;
      const float* fb1 = fb0 + HWP;
      v0 = fb0[y0*WW+x0]*w00 + fb0[y0*WW+x1]*w01 + fb0[y1*WW+x0]*w10 + fb0[y1*WW+x1]*w11;
      v1 = fb1[y0*WW+x0]*w00 + fb1[y0*WW+x1]*w01 + fb1[y1*WW+x0]*w10 + fb1[y1*WW+x1]*w11;
    }
    s_beh2[tid] = (h2){(_Float16)v0, (_Float16)v1};
  }
  __syncthreads();

  // --- BEV corner point ---
  size_t gidx = (((size_t)b * GSTR + d) * GSTR + w) * 3;
  float px = grid[gidx];
  float py = grid[gidx + 1] + (2.0f - 0.5f * (float)hc);
  float pz = grid[gidx + 2];

  // --- per-camera projection: 0 = zero, 1 = sample, 2 = behind-const ---
  int   mode[NN];
  int   off[NN];
  float fwx[NN], fwy[NN];
  bool any0 = false;
  #pragma unroll
  for (int n = 0; n < NN; ++n) {
    const float* P = &s_par[n * 32];
    float hz = P[8]*px + P[9]*py + P[10]*pz + P[11];
    int md = 0;
    if (hz > 0.f) {
      float hx = P[0]*px + P[1]*py + P[2]*pz + P[3];
      float hy = P[4]*px + P[5]*py + P[6]*pz + P[7];
      float ptx = hx / hz, pty = hy / hz;
      float fx = P[12], fy = P[13], cx = P[14], cy = P[15];
      float xn = (ptx - cx) / fx, yn = (pty - cy) / fy;
      float dx, dy;
      if (P[23] == 1.0f) {   // fisheye
        float r2 = xn*xn + yn*yn;
        float rr = sqrtf(r2);
        float th = atanf(rr);
        float t2 = th*th, t4 = t2*t2;
        float poly = 1.f + P[16]*t2 + P[17]*t4 + P[18]*(t4*t2) + P[21]*(t4*t4);
        float rad = th * poly / rr;
        dx = xn * rad * fx + cx;
        dy = yn * rad * fy + cy;
      } else {               // pinhole
        float r2 = xn*xn + yn*yn;
        float radial = 1.f + P[16]*r2 + P[17]*r2*r2 + P[18]*r2*r2*r2;
        float xp = xn*radial + 2.f*P[19]*xn*yn + P[20]*(r2 + 2.f*xn*xn);
        float yp = yn*radial + P[19]*(r2 + 2.f*yn*yn) + 2.f*P[20]*xn*yn;
        dx = xp * fx + cx;
        dy = yp * fy + cy;
      }
      float p2x = P[24]*dx + P[25]*dy + P[28];
      float p2y = P[26]*dx + P[27]*dy + P[29];
      float nx = fminf(fmaxf(2.0f * p2x / 88.0f - 1.0f, -1.f), 1.f);
      float ny = fminf(fmaxf(2.0f * p2y / 88.0f - 1.0f, -1.f), 1.f);
      bool visible = (nx > -1.f) && (nx < 1.f) && (ny > -1.f) && (ny < 1.f);
      if (visible) {
        float gx = (nx + 1.f) * 0.5f * (float)(WW - 1);
        float gy = (ny + 1.f) * 0.5f * (float)(HH - 1);
        float x0f = floorf(gx), y0f = floorf(gy);
        fwx[n] = gx - x0f;
        fwy[n] = gy - y0f;
        int x0 = (int)fminf(fmaxf(x0f, 0.f), (float)(WW - 1));
        int y0 = (int)fminf(fmaxf(y0f, 0.f), (float)(HH - 1));
        off[n] = y0 * WW + x0;
        md = 1;
      } else {
        any0 = true;
      }
    } else {
      if (P[30] != 0.f) md = 2; else any0 = true;
    }
    mode[n] = md;
  }

  // --- packed-fp16 accumulator: 32 h2 = 64 channels ---
  h2 acc2[32];
  _Float16 iv = any0 ? (_Float16)0.f : (_Float16)(-INFINITY);
  h2 inith = (h2){iv, iv};
  #pragma unroll
  for (int m = 0; m < 32; ++m) acc2[m] = inith;

  #pragma unroll
  for (int n = 0; n < NN; ++n) {
    if (mode[n] == 1) {
      float wxv = fwx[n], wyv = fwy[n];
      _Float16 hw00 = (_Float16)((1.f - wxv) * (1.f - wyv));
      _Float16 hw01 = (_Float16)(wxv * (1.f - wyv));
      _Float16 hw10 = (_Float16)((1.f - wxv) * wyv);
      _Float16 hw11 = (_Float16)(wxv * wyv);
      h2 w00h = (h2){hw00, hw00}, w01h = (h2){hw01, hw01};
      h2 w10h = (h2){hw10, hw10}, w11h = (h2){hw11, hw11};
      if (TRANS) {
        const int4* t00 = (const int4*)(featT + ((size_t)(b*NN+n)*HWP + off[n]) * CC);
        const int4* t01 = t00 + (CC/8);            // x+1 (128B = 8 int4)
        const int4* t10 = t00 + (size_t)WW*(CC/8); // y+1
        const int4* t11 = t10 + (CC/8);
        #pragma unroll
        for (int j = 0; j < 8; ++j) {
          int4 A = t00[j], B4 = t01[j], C4 = t10[j], D4 = t11[j];
          const h2* av = (const h2*)&A;
          const h2* bv = (const h2*)&B4;
          const h2* cv = (const h2*)&C4;
          const h2* dv = (const h2*)&D4;
          #pragma unroll
          for (int k = 0; k < 4; ++k) {
            h2 v = av[k]*w00h + bv[k]*w01h + cv[k]*w10h + dv[k]*w11h;
            acc2[j*4+k] = __builtin_elementwise_max(acc2[j*4+k], v);
          }
        }
      } else {
        // fallback: fp32 gather from original layout
        float w00 = (1.f - wxv) * (1.f - wyv), w01 = wxv * (1.f - wyv);
        float w10 = (1.f - wxv) * wyv,         w11 = wxv * wyv;
        const float* fb = feats + (size_t)(b*NN+n) * CC * HWP + off[n];
        #pragma unroll
        for (int m = 0; m < 32; ++m) {
          const float* p0 = fb + (size_t)(2*m) * HWP;
          const float* p1 = p0 + HWP;
          float v0 = p0[0]*w00 + p0[1]*w01 + p0[WW]*w10 + p0[WW+1]*w11;
          float v1 = p1[0]*w00 + p1[1]*w01 + p1[WW]*w10 + p1[WW+1]*w11;
          acc2[m] = __builtin_elementwise_max(acc2[m],
                        (h2){(_Float16)v0, (_Float16)v1});
        }
      }
    } else if (mode[n] == 2) {
      const h2* bp = &s_beh2[n * 32];
      #pragma unroll
      for (int m = 0; m < 32; ++m)
        acc2[m] = __builtin_elementwise_max(acc2[m], bp[m]);
    }
  }

  // --- write out[b, c*7+hc, d, w], c = 2m / 2m+1 ---
  float* op = out + (((size_t)b * OUTCH + hc) * DG + d) * DG + w;
  #pragma unroll
  for (int m = 0; m < 32; ++m) {
    op[(size_t)(2*m)   * CSTRIDE] = (float)acc2[m].x;
    op[(size_t)(2*m+1) * CSTRIDE] = (float)acc2[m].y;
  }
}

extern "C" void kernel_launch(void* const* d_in, const int* in_sizes, int n_in,
                              void* d_out, int out_size, void* d_ws, size_t ws_size,
                              hipStream_t stream) {
  const float* feats  = (const float*)d_in[0];
  const float* ks     = (const float*)d_in[1];
  const float* imu    = (const float*)d_in[2];
  const float* prots  = (const float*)d_in[3];
  const float* ptrans = (const float*)d_in[4];
  const float* und    = (const float*)d_in[5];
  const float* grid   = (const float*)d_in[6];
  float* out = (float*)d_out;

  size_t featT_bytes = (size_t)BB * NN * HWP * CC * sizeof(_Float16);
  bool trans = (d_ws != nullptr) && (ws_size >= featT_bytes);
  _Float16* featT = (_Float16*)d_ws;

  dim3 mblock(128, 2);
  dim3 mgrid(BB * HC * 64);

  if (trans) {
    transpose_feat_f16_kernel<<<BB * NN * 44, 256, 0, stream>>>(feats, featT);
    oft_main_kernel<true><<<mgrid, mblock, 0, stream>>>(
        feats, featT, ks, imu, prots, ptrans, und, grid, out);
  } else {
    oft_main_kernel<false><<<mgrid, mblock, 0, stream>>>(
        feats, featT, ks, imu, prots, ptrans, und, grid, out);
  }
}